// Round 5
// baseline (1231.911 us; speedup 1.0000x reference)
//
#include <hip/hip_runtime.h>

// Problem constants
constexpr int D  = 128;
constexpr int M  = 8192;
constexpr int L  = 5;
constexpr int K  = 8;
constexpr int KL = 4;
constexpr int G  = 4096;

constexpr int TB   = 64;            // bucket pad granularity (keeps 32-tiles uniform)
constexpr int PADL = M + K * TB;    // 8704 -> 272 row-tiles of 32
constexpr int PADG = G + KL * TB;   // 4352 -> 136 row-tiles of 32

typedef short bf16x8 __attribute__((ext_vector_type(8)));
typedef float f32x4  __attribute__((ext_vector_type(4)));

__device__ __forceinline__ unsigned short f2bf(float x) {
  union { float f; unsigned int u; } c; c.f = x;
  unsigned int u = c.u + 0x7FFF + ((c.u >> 16) & 1);   // RNE
  return (unsigned short)(u >> 16);
}
__device__ __forceinline__ float bf2f(unsigned short h) {
  union { unsigned int u; float f; } c; c.u = ((unsigned int)h) << 16;
  return c.f;
}

// ---------------------------------------------------------------------------
__global__ void leaf_gather_kernel(const int* __restrict__ leaf_ids,
                                   const float* __restrict__ emb,
                                   float* __restrict__ h0) {
  int idx = blockIdx.x * 256 + threadIdx.x;
  int n = idx >> 7, d = idx & 127;
  h0[idx] = emb[(size_t)leaf_ids[n] * D + d];
}

// out = o0 + o1 (final split-K reduction for logic layer 2)
__global__ void add_out_kernel(const float* __restrict__ o0,
                               const float* __restrict__ o1,
                               float* __restrict__ out) {
  int idx = blockIdx.x * 256 + threadIdx.x;
  out[idx] = o0[idx] + o1[idx];
}

// ---------------------------------------------------------------------------
// Bucket node indices by fid, padded to 64; pad = -1. Valid entries are a
// prefix of each bucket, so every 32-row tile is fid-uniform.
__global__ void bucket64_kernel(const int* __restrict__ nf_fid,
                                const int* __restrict__ lf_fid,
                                int* __restrict__ orders) {
  int b = blockIdx.x;
  const int* fid; int N, Kf, cap; int* out;
  if (b < L) { fid = nf_fid + b * M; N = M; Kf = K;  cap = PADL; out = orders + b * PADL; }
  else       { fid = lf_fid;         N = G; Kf = KL; cap = PADG; out = orders + L * PADL; }
  __shared__ int cnt[8];
  __shared__ int cur[8];
  int tid = threadIdx.x;
  if (tid < Kf) cnt[tid] = 0;
  __syncthreads();
  for (int i = tid; i < N; i += 256) atomicAdd(&cnt[fid[i]], 1);
  __syncthreads();
  if (tid == 0) {
    int off = 0;
    for (int k = 0; k < Kf; ++k) { cur[k] = off; off += ((cnt[k] + TB - 1) / TB) * TB; }
  }
  __syncthreads();
  for (int i = tid; i < cap; i += 256) out[i] = -1;
  __syncthreads();
  for (int i = tid; i < N; i += 256) {
    int kk = fid[i];
    int pos = atomicAdd(&cur[kk], 1);
    out[pos] = i;
  }
}

// ---------------------------------------------------------------------------
// Weight prep: W[k][KD][F] fp32 -> BT[k][F][2*KD] bf16 as [hi(KD) | lo(KD)].
__global__ void prep_kernel(const float* __restrict__ W1, const float* __restrict__ W2,
                            const float* __restrict__ W3, const float* __restrict__ Wl1,
                            const float* __restrict__ Wl2,
                            short* __restrict__ B1T, short* __restrict__ B2T,
                            short* __restrict__ B3T, short* __restrict__ BL1T,
                            short* __restrict__ BL2T) {
  int b = blockIdx.x;
  const float* W; short* BT; int KD, F;
  if      (b < 4096) { W = W1;  BT = B1T;  KD = 256; F = 512; }
  else if (b < 6144) { W = W2;  BT = B2T;  KD = 512; F = 256; b -= 4096; }
  else if (b < 7168) { W = W3;  BT = B3T;  KD = 256; F = 128; b -= 6144; }
  else if (b < 9216) { W = Wl1; BT = BL1T; KD = 256; F = 512; b -= 7168; }
  else               { W = Wl2; BT = BL2T; KD = 512; F = 128; b -= 9216; }
  int k = b / F, f = b % F;
  for (int d = threadIdx.x; d < KD; d += 256) {
    float w = W[((size_t)k * KD + d) * F + f];
    unsigned short hi = f2bf(w);
    unsigned short lo = f2bf(w - bf2f(hi));
    BT[((size_t)k * F + f) * (2 * KD) + d]      = (short)hi;
    BT[((size_t)k * F + f) * (2 * KD) + KD + d] = (short)lo;
  }
}

// ---------------------------------------------------------------------------
// Grouped GEMM, split-bf16 (logical K' = 3*KH over phys layout [hi|lo]):
//   A' segs {0,1,2} -> phys {hi, lo, hi};  B' segs -> {hi, hi, lo}
// Block: 256 thr, 32 rows x 128 cols; 4 waves side-by-side, wave tile 32x32
// (RF=2 row-frags, CF=2 col-frags). LDS 23.4 KB -> ~6 blocks/CU (TLP hides
// the per-barrier vmcnt drain across co-resident blocks).
// EPI=0: relu(acc+bias) -> split hi/lo bf16 to Aout (coalesced via LDS).
// EPI=1: acc (+bias iff z==0) -> fp32 to outz = outp + z*partStride, where z
//        = blockIdx.z selects a K-slice (split-K; consumer sums partials).
// FUSED=1: A gathered from fp32 h (h0, plus h1 if SUMIN — split-K partials).
template<int KH, int NN, int EPI, int FUSED, int SUMIN>
__global__ __launch_bounds__(256) void mfma_gemm(
    const short* __restrict__ A,
    const float* __restrict__ h0, const float* __restrict__ h1,
    const int* __restrict__ gl, const int* __restrict__ gr,
    const short* __restrict__ BT, const float* __restrict__ bias,
    short* __restrict__ Aout, float* __restrict__ outp, size_t partStride,
    const int* __restrict__ order, const int* __restrict__ fid) {
  constexpr int BK  = 64;
  constexpr int NCH = 3 * KH / BK;        // 12 or 24
  constexpr int LDA = BK + 8;             // 72 shorts -> 2-way bank alias (free)
  __shared__ __align__(16) short As[32 * LDA];
  __shared__ __align__(16) short Bs[128 * LDA];
  __shared__ int nodesS[32], liS[32], riS[32];

  const int tid = threadIdx.x;
  const int row0 = blockIdx.x * 32;
  const int ct = blockIdx.y;
  const int z  = blockIdx.z;              // K-slice (EPI==1 only)

  if (tid < 32) {
    int node = order[row0 + tid];
    nodesS[tid] = node;
    if (FUSED) {
      liS[tid] = node >= 0 ? gl[node] : 0;
      riS[tid] = node >= 0 ? gr[node] : 0;
    }
  }
  __syncthreads();
  if (nodesS[0] < 0) return;              // fully-padded tile
  const int kfn = fid[nodesS[0]];
  const short* __restrict__ Bk = BT + (size_t)kfn * NN * (2 * KH);

  const int lane = tid & 63, wave = tid >> 6;
  const int l15 = lane & 15, oct = lane >> 4;
  const int wcol = wave * 32;             // wave col base within 128

  const int ar = tid >> 3;                // A staging: 32 rows x 8 thr
  const int ag = (tid & 7) * 8;           // 8 shorts (one int4)
  const int bcol = tid >> 1;              // B staging: 128 cols x 2 thr
  const int bg = (tid & 1) * 32;          // 32 shorts (4 int4)

  const int c0 = (EPI == 1) ? z * (NCH / 2) : 0;
  const int CN = (EPI == 1) ? (NCH / 2) : NCH;

  f32x4 acc[2][2];
  #pragma unroll
  for (int i = 0; i < 2; ++i)
    #pragma unroll
    for (int j = 0; j < 2; ++j) acc[i][j] = (f32x4)0.f;

  // two prefetch register sets
  int4 A0r, A1r;
  float4 F0a, F0b, F0c, F0d, F1a, F1b, F1c, F1d;
  int4 B0r[4], B1r[4];

  auto loadB_to = [&](int c, int4* r) {
    int ko = c * BK, seg = ko / KH, wi = ko % KH;
    int pb = (seg == 2) ? KH + wi : wi;
    const int4* p = (const int4*)(Bk + (size_t)(ct * 128 + bcol) * (2 * KH) + pb + bg);
    r[0] = p[0]; r[1] = p[1]; r[2] = p[2]; r[3] = p[3];
  };
  auto loadA_to = [&](int c, int4& r0,
                      float4& fa, float4& fb, float4& fc, float4& fd) {
    int ko = c * BK, seg = ko / KH, wi = ko % KH;
    if (FUSED) {
      int dl = wi + ag;                   // 8 dims per thread
      if (nodesS[ar] >= 0) {
        size_t off = (dl < 128) ? ((size_t)liS[ar] * 128 + dl)
                                : ((size_t)riS[ar] * 128 + (dl - 128));
        const float4* p0 = (const float4*)(h0 + off);
        fa = p0[0]; fb = p0[1];
        if (SUMIN) {
          const float4* p1 = (const float4*)(h1 + off);
          fc = p1[0]; fd = p1[1];
        }
      } else {
        fa = fb = fc = fd = make_float4(0.f, 0.f, 0.f, 0.f);
      }
    } else {
      int pa = (seg == 1) ? KH + wi : wi;
      r0 = *(const int4*)(A + (size_t)(row0 + ar) * (2 * KH) + pa + ag);
    }
  };
  auto storeLDS_from = [&](int c, int4& r0,
                           float4& fa, float4& fb, float4& fc, float4& fd,
                           int4* br) {
    if (FUSED) {
      int seg = (c * BK) / KH;
      float v[8];
      ((float4*)v)[0] = fa; ((float4*)v)[1] = fb;
      if (SUMIN) {
        float w[8];
        ((float4*)w)[0] = fc; ((float4*)w)[1] = fd;
        #pragma unroll
        for (int i = 0; i < 8; ++i) v[i] += w[i];
      }
      union { unsigned short u[8]; int4 q; } o;
      if (seg != 1) {
        #pragma unroll
        for (int i = 0; i < 8; ++i) o.u[i] = f2bf(v[i]);
      } else {
        #pragma unroll
        for (int i = 0; i < 8; ++i) {
          unsigned short hh = f2bf(v[i]);
          o.u[i] = f2bf(v[i] - bf2f(hh));
        }
      }
      *(int4*)&As[ar * LDA + ag] = o.q;
    } else {
      *(int4*)&As[ar * LDA + ag] = r0;
    }
    int4* db = (int4*)&Bs[bcol * LDA + bg];
    db[0] = br[0]; db[1] = br[1]; db[2] = br[2]; db[3] = br[3];
  };
  auto compute = [&]() {
    #pragma unroll
    for (int s = 0; s < 2; ++s) {
      const int ko = s * 32 + oct * 8;
      bf16x8 a0 = *(const bf16x8*)&As[(l15) * LDA + ko];
      bf16x8 a1 = *(const bf16x8*)&As[(16 + l15) * LDA + ko];
      #pragma unroll
      for (int cf = 0; cf < 2; ++cf) {
        bf16x8 b = *(const bf16x8*)&Bs[(wcol + cf * 16 + l15) * LDA + ko];
        acc[0][cf] = __builtin_amdgcn_mfma_f32_16x16x32_bf16(a0, b, acc[0][cf], 0, 0, 0);
        acc[1][cf] = __builtin_amdgcn_mfma_f32_16x16x32_bf16(a1, b, acc[1][cf], 0, 0, 0);
      }
    }
  };

  loadA_to(c0, A0r, F0a, F0b, F0c, F0d);
  loadB_to(c0, B0r);
  loadA_to(c0 + 1, A1r, F1a, F1b, F1c, F1d);
  loadB_to(c0 + 1, B1r);
  for (int c = 0; c < CN; c += 2) {
    __syncthreads();
    storeLDS_from(c0 + c, A0r, F0a, F0b, F0c, F0d, B0r);
    __syncthreads();
    if (c + 2 < CN) { loadA_to(c0 + c + 2, A0r, F0a, F0b, F0c, F0d); loadB_to(c0 + c + 2, B0r); }
    compute();
    __syncthreads();
    storeLDS_from(c0 + c + 1, A1r, F1a, F1b, F1c, F1d, B1r);
    __syncthreads();
    if (c + 3 < CN) { loadA_to(c0 + c + 3, A1r, F1a, F1b, F1c, F1d); loadB_to(c0 + c + 3, B1r); }
    compute();
  }

  // ---- Epilogue (coalesced via LDS; Bs free after final compute)
  // C/D layout: col = l15, row = oct*4 + j (+ rf*16).
  if (EPI == 0) {
    short* Ls = (short*)Bs;               // 32 x 128 shorts = 8 KB
    #pragma unroll
    for (int part = 0; part < 2; ++part) {
      __syncthreads();
      #pragma unroll
      for (int rf = 0; rf < 2; ++rf)
        #pragma unroll
        for (int cf = 0; cf < 2; ++cf) {
          int colL = wcol + cf * 16 + l15;
          float bv = bias[kfn * NN + ct * 128 + colL];
          #pragma unroll
          for (int j = 0; j < 4; ++j) {
            int row = rf * 16 + oct * 4 + j;
            float v = fmaxf(acc[rf][cf][j] + bv, 0.f);
            unsigned short hh = f2bf(v);
            unsigned short val = (part == 0) ? hh : f2bf(v - bf2f(hh));
            Ls[row * 128 + colL] = (short)val;
          }
        }
      __syncthreads();
      int row = tid >> 3, sg = (tid & 7) * 16;      // 16 shorts = 2 int4
      const int4* src = (const int4*)&Ls[row * 128 + sg];
      int4* dst = (int4*)&Aout[(size_t)(row0 + row) * (2 * NN) + part * NN + ct * 128 + sg];
      dst[0] = src[0]; dst[1] = src[1];
    }
  } else {
    float* Lf = (float*)Bs;               // 32 x 128 floats = 16 KB
    __syncthreads();
    #pragma unroll
    for (int rf = 0; rf < 2; ++rf)
      #pragma unroll
      for (int cf = 0; cf < 2; ++cf) {
        int colL = wcol + cf * 16 + l15;
        float bv = (z == 0) ? bias[kfn * 128 + colL] : 0.f;
        #pragma unroll
        for (int j = 0; j < 4; ++j) {
          int row = rf * 16 + oct * 4 + j;
          Lf[row * 128 + colL] = acc[rf][cf][j] + bv;
        }
      }
    __syncthreads();
    float* outz = outp + (size_t)z * partStride;
    int row = tid >> 3, fo = (tid & 7) * 16;        // 16 floats = 4 float4
    int node = nodesS[row];
    if (node >= 0) {
      const float4* src = (const float4*)&Lf[row * 128 + fo];
      float4* dst = (float4*)&outz[(size_t)node * 128 + fo];
      dst[0] = src[0]; dst[1] = src[1]; dst[2] = src[2]; dst[3] = src[3];
    }
  }
}

// ---------------------------------------------------------------------------
extern "C" void kernel_launch(void* const* d_in, const int* in_sizes, int n_in,
                              void* d_out, int out_size, void* d_ws, size_t ws_size,
                              hipStream_t stream) {
  const int*   leaf_ids  = (const int*)d_in[0];
  const int*   left_idx  = (const int*)d_in[1];
  const int*   right_idx = (const int*)d_in[2];
  const int*   nf_fid    = (const int*)d_in[3];
  const int*   gt_left   = (const int*)d_in[4];
  const int*   gt_right  = (const int*)d_in[5];
  const int*   lf_fid    = (const int*)d_in[6];
  const float* emb       = (const float*)d_in[7];
  const float* W1 = (const float*)d_in[8];
  const float* b1 = (const float*)d_in[9];
  const float* W2 = (const float*)d_in[10];
  const float* b2 = (const float*)d_in[11];
  const float* W3 = (const float*)d_in[12];
  const float* b3 = (const float*)d_in[13];
  const float* Wl1 = (const float*)d_in[14];
  const float* bl1 = (const float*)d_in[15];
  const float* Wl2 = (const float*)d_in[16];
  const float* bl2 = (const float*)d_in[17];
  float* out = (float*)d_out;

  const size_t SZ_H    = (size_t)M * D * 4;           // 4 MiB
  const size_t SZ_O    = (size_t)G * D * 4;           // 2 MiB
  const size_t SZ_A1   = (size_t)PADL * 1024 * 2;
  const size_t SZ_A2   = (size_t)PADL * 512 * 2;
  const size_t SZ_B1T  = (size_t)8 * 512 * 512 * 2;
  const size_t SZ_B2T  = (size_t)8 * 256 * 1024 * 2;
  const size_t SZ_B3T  = (size_t)8 * 128 * 512 * 2;
  const size_t SZ_BL1T = (size_t)4 * 512 * 512 * 2;
  const size_t SZ_BL2T = (size_t)4 * 128 * 1024 * 2;

  char* p = (char*)d_ws;
  float* hA  = (float*)p;  p += SZ_H;
  float* p0  = (float*)p;  p += SZ_H;   // partial pair A
  float* p1  = (float*)p;  p += SZ_H;
  float* q0  = (float*)p;  p += SZ_H;   // partial pair B
  float* q1  = (float*)p;  p += SZ_H;
  float* o0  = (float*)p;  p += SZ_O;   // logic2 partials
  float* o1  = (float*)p;  p += SZ_O;
  short* a1s = (short*)p;  p += SZ_A1;
  short* a2s = (short*)p;  p += SZ_A2;
  short* B1T  = (short*)p; p += SZ_B1T;
  short* B2T  = (short*)p; p += SZ_B2T;
  short* B3T  = (short*)p; p += SZ_B3T;
  short* BL1T = (short*)p; p += SZ_BL1T;
  short* BL2T = (short*)p; p += SZ_BL2T;
  int*   orders = (int*)p;

  leaf_gather_kernel<<<(M * D) / 256, 256, 0, stream>>>(leaf_ids, emb, hA);
  bucket64_kernel<<<L + 1, 256, 0, stream>>>(nf_fid, lf_fid, orders);
  prep_kernel<<<9728, 256, 0, stream>>>(W1, W2, W3, Wl1, Wl2,
                                        B1T, B2T, B3T, BL1T, BL2T);

  const size_t HSTRIDE = (size_t)M * D;   // floats between split-K partials
  // level l: input partials (in0,in1) [or hA for l=0], output partials (ou0,ou1)
  float* in0 = hA; float* in1 = nullptr;
  float* ou0 = q0; float* ou1 = q1;
  for (int l = 0; l < L; ++l) {
    const int* ord = orders + l * PADL;
    const int* fidl = nf_fid + l * M;
    if (l == 0) {
      mfma_gemm<256, 512, 0, 1, 0><<<dim3(PADL / 32, 4, 1), 256, 0, stream>>>(
          nullptr, in0, nullptr, left_idx + l * M, right_idx + l * M,
          B1T, b1, a1s, nullptr, 0, ord, fidl);
    } else {
      mfma_gemm<256, 512, 0, 1, 1><<<dim3(PADL / 32, 4, 1), 256, 0, stream>>>(
          nullptr, in0, in1, left_idx + l * M, right_idx + l * M,
          B1T, b1, a1s, nullptr, 0, ord, fidl);
    }
    mfma_gemm<512, 256, 0, 0, 0><<<dim3(PADL / 32, 2, 1), 256, 0, stream>>>(
        a1s, nullptr, nullptr, nullptr, nullptr,
        B2T, b2, a2s, nullptr, 0, ord, fidl);
    mfma_gemm<256, 128, 1, 0, 0><<<dim3(PADL / 32, 1, 2), 256, 0, stream>>>(
        a2s, nullptr, nullptr, nullptr, nullptr,
        B3T, b3, nullptr, ou0, HSTRIDE, ord, fidl);
    in0 = ou0; in1 = ou1;
    if (ou0 == q0) { ou0 = p0; ou1 = p1; } else { ou0 = q0; ou1 = q1; }
  }
  const int* ordG = orders + L * PADL;
  mfma_gemm<256, 512, 0, 1, 1><<<dim3(PADG / 32, 4, 1), 256, 0, stream>>>(
      nullptr, in0, in1, gt_left, gt_right,
      BL1T, bl1, a1s, nullptr, 0, ordG, lf_fid);
  mfma_gemm<512, 128, 1, 0, 0><<<dim3(PADG / 32, 1, 2), 256, 0, stream>>>(
      a1s, nullptr, nullptr, nullptr, nullptr,
      BL2T, bl2, nullptr, o0, (size_t)G * D, ordG, lf_fid);
  add_out_kernel<<<(G * D) / 256, 256, 0, stream>>>(o0, o1, out);
}